// Round 5
// baseline (273.827 us; speedup 1.0000x reference)
//
#include <hip/hip_runtime.h>
#include <math.h>

// PyramidROIAlign: B=2, N=1000, C=256, POOL=7x7
// p3: [2,128,128,256], p4: [2,64,64,256], p5: [2,32,32,256], all fp32 NHWC.
// Output: [2,1000,7,7,256] fp32.
//
// R7: occupancy-cliff fix. R4/R6 analysis: kernel is concurrency-bound,
// not BW-bound (4 TB/s while fills hit 6.8; fetch cut 142->85 MB bought
// no time). Block lifetime ~15us with only 14 resident waves/CU (occ 44%):
// VGPR_Count=72 is 8 regs over the 64-VGPR occupancy cliff (waves/CU
// halves at >64 VGPRs), so only 2 of the 7-wave blocks fit per CU and
// their waves move in lockstep bursts (issue 28 loads -> all drain vmcnt
// -> blend -> store) leaving issue-dead windows.
// Fix: __launch_bounds__(448, 8) -> compiler register budget 512/8 = 64
// VGPRs -> 4 blocks (28 waves)/CU, phase-staggered across blocks.
// Keep R6's counting-sort + direct perm[bid] order (proven FETCH 142->85MB;
// chip-wide sweep of sorted (level,batch,y-band) sequence, auto-balanced).
//
// Mapping: one block (448 thr = 7 waves) per box; wave = pool row iy;
// lane covers 4 channels (vec4). Three-phase body; compiler chunks the
// 28-load phase 2 to fit the 64-reg budget (still ~8+ loads in flight/wave).

#define N_PER_B 1000
#define NBOX    2000   // B*N
#define CCH     256
#define PH      7
#define PW      7

// buckets: ((level-3)*2 + batch)*16 + yband  -> 3*2*16 = 96
#define NBUCKET 96

typedef float f4 __attribute__((ext_vector_type(4)));

__device__ __forceinline__ int box_level(float h, float w) {
    // roi_level = clip(ceil(5 + log(h*w)/log(2)), 3, 5) -- match ref op order
    const float lvl  = ceilf(5.0f + logf(h * w) / 0.69314718055994530942f);
    const float lvlc = fminf(fmaxf(lvl, 3.0f), 5.0f);
    return (int)lvlc;
}

// ---------------- sort pre-kernel: counting sort into perm ----------------
__global__ __launch_bounds__(1024) void sort_boxes_kernel(
    const float* __restrict__ boxes, int* __restrict__ perm)
{
    __shared__ int cnt[NBUCKET];
    __shared__ int base[NBUCKET];
    const int t = threadIdx.x;
    if (t < NBUCKET) cnt[t] = 0;
    __syncthreads();

    int mykey[2];
#pragma unroll
    for (int i = 0; i < 2; ++i) {
        const int box = t + i * 1024;
        int key = -1;
        if (box < NBOX) {
            const float y1 = boxes[box * 4 + 0];
            const float x1 = boxes[box * 4 + 1];
            const float y2 = boxes[box * 4 + 2];
            const float x2 = boxes[box * 4 + 3];
            const int level = box_level(y2 - y1, x2 - x1);
            const int b     = (box >= N_PER_B) ? 1 : 0;
            const float cy  = 0.5f * (y1 + y2);   // normalized box center
            const int yband = (int)fminf(fmaxf(cy * 16.0f, 0.0f), 15.0f);
            key = ((level - 3) * 2 + b) * 16 + yband;
            atomicAdd(&cnt[key], 1);
        }
        mykey[i] = key;
    }
    __syncthreads();
    if (t == 0) {
        int acc = 0;
        for (int k = 0; k < NBUCKET; ++k) { base[k] = acc; acc += cnt[k]; }
    }
    __syncthreads();
#pragma unroll
    for (int i = 0; i < 2; ++i) {
        const int box = t + i * 1024;
        if (box < NBOX) {
            const int pos = atomicAdd(&base[mykey[i]], 1);
            perm[pos] = box;
        }
    }
}

// ---------------- main kernel ----------------
__global__ __launch_bounds__(448, 8) void pyramid_roi_align_kernel(
    const float* __restrict__ boxes,   // [2000,4] y1,x1,y2,x2
    const float* __restrict__ p3,      // [2,128,128,256]
    const float* __restrict__ p4,      // [2,64,64,256]
    const float* __restrict__ p5,      // [2,32,32,256]
    const int*   __restrict__ perm,    // [2000] sorted box order (or null)
    float* __restrict__ out)           // [2000,49,256]
{
    // Direct sorted order: consecutive bids are dispatched round-robin
    // across XCDs in time order, so the whole chip sweeps the sorted
    // sequence together (chip-wide temporal locality + auto load balance).
    const int bid = blockIdx.x;
    const int box = perm ? perm[bid] : bid;

    const int iy   = threadIdx.x >> 6;   // wave id = pool row, 0..6
    const int lane = threadIdx.x & 63;
    const int c    = lane * 4;

    // ---- per-box setup (wave-uniform) ----
    const float y1 = boxes[box * 4 + 0];
    const float x1 = boxes[box * 4 + 1];
    const float y2 = boxes[box * 4 + 2];
    const float x2 = boxes[box * 4 + 3];
    const float h  = y2 - y1;
    const float w  = x2 - x1;

    const int level = box_level(h, w);

    const float* feat;
    int H;
    if (level <= 3)      { feat = p3; H = 128; }
    else if (level == 4) { feat = p4; H = 64;  }
    else                 { feat = p5; H = 32;  }
    const int W = H;

    const int b = (box >= N_PER_B) ? 1 : 0;
    feat += (size_t)b * H * W * CCH;

    const float Hm1 = (float)(H - 1);
    const float Wm1 = (float)(W - 1);

    // ys = y1*(H-1) + iy * ((y2-y1)*(H-1)/6)   (match reference exactly)
    const float ys = y1 * Hm1 + (float)iy * (h * Hm1 / 6.0f);
    const bool  vy = (ys >= 0.0f) && (ys <= Hm1);

    const float y0f = floorf(ys);
    const float wy  = ys - y0f;
    const float omwy = 1.0f - wy;

    const int y0i = (int)fminf(fmaxf(y0f,        0.0f), Hm1);
    const int y1i = (int)fminf(fmaxf(y0f + 1.0f, 0.0f), Hm1);

    const float* row0 = feat + (size_t)y0i * W * CCH + c;  // top row
    const float* row1 = feat + (size_t)y1i * W * CCH + c;  // bottom row

    const float xstep = w * Wm1 / 6.0f;

    // ---- phase 1: all column indices / weights (no memory ops) ----
    int   x0i[PW], x1i[PW];
    float wxv[PW];
    bool  vx[PW];
#pragma unroll
    for (int ix = 0; ix < PW; ++ix) {
        const float xs = x1 * Wm1 + (float)ix * xstep;
        vx[ix] = (xs >= 0.0f) && (xs <= Wm1);
        const float x0f = floorf(xs);
        wxv[ix] = xs - x0f;
        x0i[ix] = (int)fminf(fmaxf(x0f,        0.0f), Wm1);
        x1i[ix] = (int)fminf(fmaxf(x0f + 1.0f, 0.0f), Wm1);
    }

    // ---- phase 2: issue corner loads (compiler chunks under 64-reg budget) ----
    f4 v00[PW], v01[PW], v10[PW], v11[PW];
#pragma unroll
    for (int ix = 0; ix < PW; ++ix) {
        v00[ix] = *(const f4*)(row0 + (size_t)x0i[ix] * CCH);
        v01[ix] = *(const f4*)(row0 + (size_t)x1i[ix] * CCH);
        v10[ix] = *(const f4*)(row1 + (size_t)x0i[ix] * CCH);
        v11[ix] = *(const f4*)(row1 + (size_t)x1i[ix] * CCH);
    }

    float* dst_base = out + ((size_t)box * (PH * PW) + (size_t)iy * PW) * CCH + c;

    // ---- phase 3: blend + store ----
#pragma unroll
    for (int ix = 0; ix < PW; ++ix) {
        const float wx   = wxv[ix];
        const float omwx = 1.0f - wx;

        f4 res = (v00[ix] * omwx + v01[ix] * wx) * omwy
               + (v10[ix] * omwx + v11[ix] * wx) * wy;

        if (!(vy && vx[ix])) res = (f4)(0.0f);

        *(f4*)(dst_base + (size_t)ix * CCH) = res;
    }
}

extern "C" void kernel_launch(void* const* d_in, const int* in_sizes, int n_in,
                              void* d_out, int out_size, void* d_ws, size_t ws_size,
                              hipStream_t stream) {
    const float* boxes = (const float*)d_in[0];
    // d_in[1] = positive_indices (unused by reference)
    const float* p3 = (const float*)d_in[2];
    const float* p4 = (const float*)d_in[3];
    const float* p5 = (const float*)d_in[4];
    // d_in[5] = config (unused)
    float* out = (float*)d_out;

    int* perm = nullptr;
    if (d_ws != nullptr && ws_size >= (size_t)NBOX * sizeof(int)) {
        perm = (int*)d_ws;
        hipLaunchKernelGGL(sort_boxes_kernel, dim3(1), dim3(1024), 0, stream,
                           boxes, perm);
    }

    hipLaunchKernelGGL(pyramid_roi_align_kernel, dim3(NBOX), dim3(448), 0, stream,
                       boxes, p3, p4, p5, perm, out);
}

// Round 6
// 172.359 us; speedup vs baseline: 1.5887x; 1.5887x over previous
//
#include <hip/hip_runtime.h>
#include <math.h>

// PyramidROIAlign: B=2, N=1000, C=256, POOL=7x7
// p3: [2,128,128,256], p4: [2,64,64,256], p5: [2,32,32,256], all fp32 NHWC.
// Output: [2,1000,7,7,256] fp32.
//
// R8: fit the 64-VGPR occupancy cliff WITHOUT spilling.
// R7 post-mortem: __launch_bounds__(448,8) + 28-live-float4 arrays ->
// allocator spilled to scratch (VGPR 32, WRITE 98->357MB, FETCH 85->282MB,
// kernel 160us). Occupancy DID hit 62.8% -> the 4-blocks/CU mechanism is
// real; only the register footprint was wrong.
// Fix: explicit depth-2 software pipeline, fully unrolled, named registers
// (no runtime-indexed arrays): load column ix+1's 4 corners, then blend +
// store column ix. Vector liveness = 8 float4 (32 regs) + pointers + wy.
// All x-geometry (x0i/x1i/wx/vx) depends only on box -> block-uniform ->
// compiler scalarizes into SGPRs. Expect ~50-60 VGPR, no scratch,
// 4 blocks (28 waves)/CU, steady-state vmcnt(4): b-loads in flight while
// a-column blends.
// Keep R6's counting-sort + direct perm[bid] (FETCH 142->85MB, chip-wide
// sweep of sorted (level,batch,y-band) sequence, auto load balance).

#define N_PER_B 1000
#define NBOX    2000   // B*N
#define CCH     256
#define PH      7
#define PW      7

// buckets: ((level-3)*2 + batch)*16 + yband  -> 3*2*16 = 96
#define NBUCKET 96

typedef float f4 __attribute__((ext_vector_type(4)));

__device__ __forceinline__ int box_level(float h, float w) {
    // roi_level = clip(ceil(5 + log(h*w)/log(2)), 3, 5) -- match ref op order
    const float lvl  = ceilf(5.0f + logf(h * w) / 0.69314718055994530942f);
    const float lvlc = fminf(fmaxf(lvl, 3.0f), 5.0f);
    return (int)lvlc;
}

// ---------------- sort pre-kernel: counting sort into perm ----------------
__global__ __launch_bounds__(1024) void sort_boxes_kernel(
    const float* __restrict__ boxes, int* __restrict__ perm)
{
    __shared__ int cnt[NBUCKET];
    __shared__ int base[NBUCKET];
    const int t = threadIdx.x;
    if (t < NBUCKET) cnt[t] = 0;
    __syncthreads();

    int mykey[2];
#pragma unroll
    for (int i = 0; i < 2; ++i) {
        const int box = t + i * 1024;
        int key = -1;
        if (box < NBOX) {
            const float y1 = boxes[box * 4 + 0];
            const float x1 = boxes[box * 4 + 1];
            const float y2 = boxes[box * 4 + 2];
            const float x2 = boxes[box * 4 + 3];
            const int level = box_level(y2 - y1, x2 - x1);
            const int b     = (box >= N_PER_B) ? 1 : 0;
            const float cy  = 0.5f * (y1 + y2);   // normalized box center
            const int yband = (int)fminf(fmaxf(cy * 16.0f, 0.0f), 15.0f);
            key = ((level - 3) * 2 + b) * 16 + yband;
            atomicAdd(&cnt[key], 1);
        }
        mykey[i] = key;
    }
    __syncthreads();
    if (t == 0) {
        int acc = 0;
        for (int k = 0; k < NBUCKET; ++k) { base[k] = acc; acc += cnt[k]; }
    }
    __syncthreads();
#pragma unroll
    for (int i = 0; i < 2; ++i) {
        const int box = t + i * 1024;
        if (box < NBOX) {
            const int pos = atomicAdd(&base[mykey[i]], 1);
            perm[pos] = box;
        }
    }
}

// ---------------- main kernel ----------------
__global__ __launch_bounds__(448, 8) void pyramid_roi_align_kernel(
    const float* __restrict__ boxes,   // [2000,4] y1,x1,y2,x2
    const float* __restrict__ p3,      // [2,128,128,256]
    const float* __restrict__ p4,      // [2,64,64,256]
    const float* __restrict__ p5,      // [2,32,32,256]
    const int*   __restrict__ perm,    // [2000] sorted box order (or null)
    float* __restrict__ out)           // [2000,49,256]
{
    // Direct sorted order: consecutive bids round-robin across XCDs in
    // dispatch-time order -> whole chip sweeps the sorted sequence together.
    const int bid = blockIdx.x;
    const int box = perm ? perm[bid] : bid;

    const int iy   = threadIdx.x >> 6;   // wave id = pool row, 0..6
    const int lane = threadIdx.x & 63;
    const int c    = lane * 4;

    // ---- per-box setup (block-uniform -> SGPRs) ----
    const float y1 = boxes[box * 4 + 0];
    const float x1 = boxes[box * 4 + 1];
    const float y2 = boxes[box * 4 + 2];
    const float x2 = boxes[box * 4 + 3];
    const float h  = y2 - y1;
    const float w  = x2 - x1;

    const int level = box_level(h, w);

    const float* feat;
    int H;
    if (level <= 3)      { feat = p3; H = 128; }
    else if (level == 4) { feat = p4; H = 64;  }
    else                 { feat = p5; H = 32;  }
    const int W = H;

    const int b = (box >= N_PER_B) ? 1 : 0;
    feat += (size_t)b * H * W * CCH;

    const float Hm1 = (float)(H - 1);
    const float Wm1 = (float)(W - 1);

    // ---- per-wave y geometry ----
    // ys = y1*(H-1) + iy * ((y2-y1)*(H-1)/6)   (match reference exactly)
    const float ys = y1 * Hm1 + (float)iy * (h * Hm1 / 6.0f);
    const bool  vy = (ys >= 0.0f) && (ys <= Hm1);

    const float y0f = floorf(ys);
    const float wy  = ys - y0f;
    const float omwy = 1.0f - wy;

    const int y0i = (int)fminf(fmaxf(y0f,        0.0f), Hm1);
    const int y1i = (int)fminf(fmaxf(y0f + 1.0f, 0.0f), Hm1);

    const float* row0 = feat + (size_t)y0i * W * CCH + c;  // top row
    const float* row1 = feat + (size_t)y1i * W * CCH + c;  // bottom row

    const float xstep = w * Wm1 / 6.0f;
    float* dst = out + ((size_t)box * (PH * PW) + (size_t)iy * PW) * CCH + c;

    // Column geometry (block-uniform): byte offsets into a feature row.
    auto colx = [&](int ix, int& off0, int& off1, float& wx, bool& vxv) {
        const float xs = x1 * Wm1 + (float)ix * xstep;
        vxv = (xs >= 0.0f) && (xs <= Wm1);
        const float x0f = floorf(xs);
        wx  = xs - x0f;
        off0 = (int)fminf(fmaxf(x0f,        0.0f), Wm1) * CCH;
        off1 = (int)fminf(fmaxf(x0f + 1.0f, 0.0f), Wm1) * CCH;
    };

    // ---- depth-2 software pipeline over the 7 columns ----
    int   o0, o1;  float wx;  bool vx;
    colx(0, o0, o1, wx, vx);
    f4 a00 = *(const f4*)(row0 + o0);
    f4 a01 = *(const f4*)(row0 + o1);
    f4 a10 = *(const f4*)(row1 + o0);
    f4 a11 = *(const f4*)(row1 + o1);

#pragma unroll
    for (int ix = 0; ix < PW; ++ix) {
        int   n0 = 0, n1 = 0;  float wxn = 0.0f;  bool vxn = false;
        f4 b00, b01, b10, b11;
        if (ix + 1 < PW) {
            colx(ix + 1, n0, n1, wxn, vxn);
            b00 = *(const f4*)(row0 + n0);
            b01 = *(const f4*)(row0 + n1);
            b10 = *(const f4*)(row1 + n0);
            b11 = *(const f4*)(row1 + n1);
        }

        const float omwx = 1.0f - wx;
        f4 res = (a00 * omwx + a01 * wx) * omwy
               + (a10 * omwx + a11 * wx) * wy;
        if (!(vy && vx)) res = (f4)(0.0f);
        *(f4*)(dst + (size_t)ix * CCH) = res;

        if (ix + 1 < PW) {
            a00 = b00; a01 = b01; a10 = b10; a11 = b11;
            wx = wxn; vx = vxn;
        }
    }
}

extern "C" void kernel_launch(void* const* d_in, const int* in_sizes, int n_in,
                              void* d_out, int out_size, void* d_ws, size_t ws_size,
                              hipStream_t stream) {
    const float* boxes = (const float*)d_in[0];
    // d_in[1] = positive_indices (unused by reference)
    const float* p3 = (const float*)d_in[2];
    const float* p4 = (const float*)d_in[3];
    const float* p5 = (const float*)d_in[4];
    // d_in[5] = config (unused)
    float* out = (float*)d_out;

    int* perm = nullptr;
    if (d_ws != nullptr && ws_size >= (size_t)NBOX * sizeof(int)) {
        perm = (int*)d_ws;
        hipLaunchKernelGGL(sort_boxes_kernel, dim3(1), dim3(1024), 0, stream,
                           boxes, perm);
    }

    hipLaunchKernelGGL(pyramid_roi_align_kernel, dim3(NBOX), dim3(448), 0, stream,
                       boxes, p3, p4, p5, perm, out);
}

// Round 7
// 169.639 us; speedup vs baseline: 1.6142x; 1.0160x over previous
//
#include <hip/hip_runtime.h>
#include <math.h>

// PyramidROIAlign: B=2, N=1000, C=256, POOL=7x7
// p3: [2,128,128,256], p4: [2,64,64,256], p5: [2,32,32,256], all fp32 NHWC.
// Output: [2,1000,7,7,256] fp32.
//
// R9: subtraction round. Cross-round evidence (R2..R8): kernel pinned at
// ~57-60us regardless of MLP depth, occupancy (44->~80%), fetch traffic
// (142->85MB via sort), NT stores -> the sorted-locality pre-kernel bought
// ~0 kernel time (not BW-bound at this traffic) while costing ~4us of
// serial dispatch overhead. Remove sort+perm entirely; keep the best
// kernel structure (depth-2 pipeline, named regs, (448,8) proven
// spill-free in R8 -- a spill would have topped the profile like R7's
// 160-200us, and it didn't appear at all).
// Also: load the box as one f4 (16B aligned) instead of 4 scalar floats.
//
// Mapping: one block (448 thr = 7 waves) per box; wave = pool row iy;
// lane covers 4 channels (vec4). Depth-2 software pipeline over columns:
// load column ix+1's 4 corners while blending/storing column ix.
// Vector liveness ~8 f4 + pointers -> fits the 64-VGPR / 4-blocks-per-CU
// occupancy tier.

#define N_PER_B 1000
#define NBOX    2000   // B*N
#define CCH     256
#define PH      7
#define PW      7

typedef float f4 __attribute__((ext_vector_type(4)));

__global__ __launch_bounds__(448, 8) void pyramid_roi_align_kernel(
    const float* __restrict__ boxes,   // [2000,4] y1,x1,y2,x2
    const float* __restrict__ p3,      // [2,128,128,256]
    const float* __restrict__ p4,      // [2,64,64,256]
    const float* __restrict__ p5,      // [2,32,32,256]
    float* __restrict__ out)           // [2000,49,256]
{
    const int box  = blockIdx.x;
    const int iy   = threadIdx.x >> 6;   // wave id = pool row, 0..6
    const int lane = threadIdx.x & 63;
    const int c    = lane * 4;

    // ---- per-box setup (block-uniform -> scalarized) ----
    const f4 bx = *(const f4*)(boxes + box * 4);
    const float y1 = bx.x;
    const float x1 = bx.y;
    const float y2 = bx.z;
    const float x2 = bx.w;
    const float h  = y2 - y1;
    const float w  = x2 - x1;

    // roi_level = clip(ceil(5 + log(h*w)/log(2)), 3, 5) -- match ref op order
    const float lvl  = ceilf(5.0f + logf(h * w) / 0.69314718055994530942f);
    const float lvlc = fminf(fmaxf(lvl, 3.0f), 5.0f);
    const int level  = (int)lvlc;

    const float* feat;
    int H;
    if (level <= 3)      { feat = p3; H = 128; }
    else if (level == 4) { feat = p4; H = 64;  }
    else                 { feat = p5; H = 32;  }
    const int W = H;

    const int b = (box >= N_PER_B) ? 1 : 0;
    feat += (size_t)b * H * W * CCH;

    const float Hm1 = (float)(H - 1);
    const float Wm1 = (float)(W - 1);

    // ---- per-wave y geometry ----
    // ys = y1*(H-1) + iy * ((y2-y1)*(H-1)/6)   (match reference exactly)
    const float ys = y1 * Hm1 + (float)iy * (h * Hm1 / 6.0f);
    const bool  vy = (ys >= 0.0f) && (ys <= Hm1);

    const float y0f = floorf(ys);
    const float wy  = ys - y0f;
    const float omwy = 1.0f - wy;

    const int y0i = (int)fminf(fmaxf(y0f,        0.0f), Hm1);
    const int y1i = (int)fminf(fmaxf(y0f + 1.0f, 0.0f), Hm1);

    const float* row0 = feat + (size_t)y0i * W * CCH + c;  // top row
    const float* row1 = feat + (size_t)y1i * W * CCH + c;  // bottom row

    const float xstep = w * Wm1 / 6.0f;
    float* dst = out + ((size_t)box * (PH * PW) + (size_t)iy * PW) * CCH + c;

    // Column geometry (block-uniform): element offsets into a feature row.
    auto colx = [&](int ix, int& off0, int& off1, float& wx, bool& vxv) {
        const float xs = x1 * Wm1 + (float)ix * xstep;
        vxv = (xs >= 0.0f) && (xs <= Wm1);
        const float x0f = floorf(xs);
        wx  = xs - x0f;
        off0 = (int)fminf(fmaxf(x0f,        0.0f), Wm1) * CCH;
        off1 = (int)fminf(fmaxf(x0f + 1.0f, 0.0f), Wm1) * CCH;
    };

    // ---- depth-2 software pipeline over the 7 columns ----
    int   o0, o1;  float wx;  bool vx;
    colx(0, o0, o1, wx, vx);
    f4 a00 = *(const f4*)(row0 + o0);
    f4 a01 = *(const f4*)(row0 + o1);
    f4 a10 = *(const f4*)(row1 + o0);
    f4 a11 = *(const f4*)(row1 + o1);

#pragma unroll
    for (int ix = 0; ix < PW; ++ix) {
        int   n0 = 0, n1 = 0;  float wxn = 0.0f;  bool vxn = false;
        f4 b00, b01, b10, b11;
        if (ix + 1 < PW) {
            colx(ix + 1, n0, n1, wxn, vxn);
            b00 = *(const f4*)(row0 + n0);
            b01 = *(const f4*)(row0 + n1);
            b10 = *(const f4*)(row1 + n0);
            b11 = *(const f4*)(row1 + n1);
        }

        const float omwx = 1.0f - wx;
        f4 res = (a00 * omwx + a01 * wx) * omwy
               + (a10 * omwx + a11 * wx) * wy;
        if (!(vy && vx)) res = (f4)(0.0f);
        *(f4*)(dst + (size_t)ix * CCH) = res;

        if (ix + 1 < PW) {
            a00 = b00; a01 = b01; a10 = b10; a11 = b11;
            wx = wxn; vx = vxn;
        }
    }
}

extern "C" void kernel_launch(void* const* d_in, const int* in_sizes, int n_in,
                              void* d_out, int out_size, void* d_ws, size_t ws_size,
                              hipStream_t stream) {
    const float* boxes = (const float*)d_in[0];
    // d_in[1] = positive_indices (unused by reference)
    const float* p3 = (const float*)d_in[2];
    const float* p4 = (const float*)d_in[3];
    const float* p5 = (const float*)d_in[4];
    // d_in[5] = config (unused)
    float* out = (float*)d_out;

    hipLaunchKernelGGL(pyramid_roi_align_kernel, dim3(NBOX), dim3(448), 0, stream,
                       boxes, p3, p4, p5, out);
}